// Round 1
// 514.563 us; speedup vs baseline: 1.4379x; 1.4379x over previous
//
#include <hip/hip_runtime.h>

#define NY 512
#define NX 512
#define NSHOT 4
#define NSRC 2
#define NREC 64
#define NT 32
#define DXF 5.0f
#define DTF 0.0005f
#define PML_W 20
#define C1F 1.125f
#define C2F (-1.0f/24.0f)

// PML strips: sigma>0 (hence a!=0) only for index in [0,20) or [NY-PML_W, NY).
// Outside the strips a==0, so m = b*m stays identically 0 given zero init —
// skip the m-field load/update/store there entirely (saves ~half the traffic).
__device__ __forceinline__ bool in_pml(int i) {
    return (i < PML_W) | (i >= NY - PML_W);
}

__device__ __forceinline__ float ldz(const float* __restrict__ f, int sbase, int y, int x) {
    // zero-padded load (reference pads with zeros outside the domain)
    return ((unsigned)y < (unsigned)NY && (unsigned)x < (unsigned)NX)
               ? f[sbase + y * NX + x] : 0.0f;
}

// XCD-aware bijective block swizzle (T1). Grid = (2, 512, 4) = 4096 blocks,
// 4096 % 8 == 0 so the simple remap is bijective. The HW round-robins flat
// block ids across the 8 XCDs (flat % 8 == XCD); we invert that so each XCD
// owns a contiguous half-shot band: XCD k -> shot k/2, rows (k%2)*256..+256.
// Per-XCD per-kernel working set ~3-4 MB -> fits the 4 MB XCD-local L2,
// including the vel->stress->vel producer/consumer reuse (same map in both
// kernels).
__device__ __forceinline__ void swizzle_block(int& s, int& y, int& xb) {
    int flat = (int)blockIdx.x + 2 * ((int)blockIdx.y + 512 * (int)blockIdx.z);
    int xcd   = flat & 7;
    int local = flat >> 3;          // 0..511 within the XCD
    int c = xcd * 512 + local;      // contiguous chunk per XCD
    xb = c & 1;                     // x-half fastest
    y  = (c >> 1) & 511;
    s  = c >> 10;
}

__global__ void init_profiles(float* __restrict__ pa, float* __restrict__ pb) {
    int i = blockIdx.x * blockDim.x + threadIdx.x;
    if (i >= NY) return;
    float w = (float)PML_W;
    float x = (float)i;
    float frac = fmaxf((w - x) / w, (x - (float)(NY - 1 - PML_W)) / w);
    frac = fminf(fmaxf(frac, 0.0f), 1.0f);
    float sigma = 3.0f * 3500.0f * 6.9077553f / (2.0f * w * DXF) * frac * frac;
    float alpha = 78.539816f; // pi * 25
    float b = __expf(-(sigma + alpha) * DTF);
    pb[i] = b;
    pa[i] = sigma / (sigma + alpha) * (b - 1.0f);
}

__global__ __launch_bounds__(256) void vel_kernel(
    const float* __restrict__ syy, const float* __restrict__ sxy, const float* __restrict__ sxx,
    float* __restrict__ vy, float* __restrict__ vx,
    float* __restrict__ m_syyy, float* __restrict__ m_sxyy,
    float* __restrict__ m_sxyx, float* __restrict__ m_sxxx,
    const float* __restrict__ buoy,
    const float* __restrict__ pa, const float* __restrict__ pb,
    const float* __restrict__ amps, const int* __restrict__ srcloc, int t)
{
    int s, y, xb;
    swizzle_block(s, y, xb);
    int x = xb * 256 + threadIdx.x;
    int sbase = s * NY * NX;
    int idx = sbase + y * NX + x;
    const float inv_dx = 1.0f / DXF;

    // dsyy = diff_minus(syy, y): C1*(f[y]-f[y-1]) + C2*(f[y+1]-f[y-2])
    float syy_0  = syy[idx];
    float syy_m1 = ldz(syy, sbase, y - 1, x);
    float syy_m2 = ldz(syy, sbase, y - 2, x);
    float syy_p1 = ldz(syy, sbase, y + 1, x);
    float dsyy = (C1F * (syy_0 - syy_m1) + C2F * (syy_p1 - syy_m2)) * inv_dx;

    // dsxy_x = diff_plus(sxy, x): C1*(f[x+1]-f[x]) + C2*(f[x+2]-f[x-1])
    float sxy_0   = sxy[idx];
    float sxy_xm1 = ldz(sxy, sbase, y, x - 1);
    float sxy_xp1 = ldz(sxy, sbase, y, x + 1);
    float sxy_xp2 = ldz(sxy, sbase, y, x + 2);
    float dsxy_x = (C1F * (sxy_xp1 - sxy_0) + C2F * (sxy_xp2 - sxy_xm1)) * inv_dx;

    // dsxy_y = diff_plus(sxy, y)
    float sxy_ym1 = ldz(sxy, sbase, y - 1, x);
    float sxy_yp1 = ldz(sxy, sbase, y + 1, x);
    float sxy_yp2 = ldz(sxy, sbase, y + 2, x);
    float dsxy_y = (C1F * (sxy_yp1 - sxy_0) + C2F * (sxy_yp2 - sxy_ym1)) * inv_dx;

    // dsxx = diff_minus(sxx, x)
    float sxx_0   = sxx[idx];
    float sxx_xm1 = ldz(sxx, sbase, y, x - 1);
    float sxx_xm2 = ldz(sxx, sbase, y, x - 2);
    float sxx_xp1 = ldz(sxx, sbase, y, x + 1);
    float dsxx = (C1F * (sxx_0 - sxx_xm1) + C2F * (sxx_xp1 - sxx_xm2)) * inv_dx;

    // y-direction PML memory fields (uniform branch: y uniform per block)
    float msyyy = 0.0f, msxyy = 0.0f;
    if (in_pml(y)) {
        float ay = pa[y], by = pb[y];
        msyyy = by * m_syyy[idx] + ay * dsyy;   m_syyy[idx] = msyyy;
        msxyy = by * m_sxyy[idx] + ay * dsxy_y; m_sxyy[idx] = msxyy;
    }
    // x-direction PML memory fields (lane-masked; untouched cache lines skipped)
    float msxyx = 0.0f, msxxx = 0.0f;
    if (in_pml(x)) {
        float ax = pa[x], bx = pb[x];
        msxyx = bx * m_sxyx[idx] + ax * dsxy_x; m_sxyx[idx] = msxyx;
        msxxx = bx * m_sxxx[idx] + ax * dsxx;   m_sxxx[idx] = msxxx;
    }

    float b = buoy[y * NX + x];
    float vy_new = vy[idx] + DTF * b * ((dsyy + msyyy) + (dsxy_x + msxyx));
    vx[idx] += DTF * b * ((dsxy_y + msxyy) + (dsxx + msxxx));

    // source injection (after velocity update, before stress pass reads vy)
#pragma unroll
    for (int i = 0; i < NSRC; ++i) {
        int sy = srcloc[(s * NSRC + i) * 2 + 0];
        int sx = srcloc[(s * NSRC + i) * 2 + 1];
        if (sy == y && sx == x) {
            vy_new += amps[(s * NSRC + i) * NT + t] * DTF * b;
        }
    }
    vy[idx] = vy_new;
}

__global__ __launch_bounds__(256) void stress_kernel(
    const float* __restrict__ vy, const float* __restrict__ vx,
    float* __restrict__ syy, float* __restrict__ sxy, float* __restrict__ sxx,
    float* __restrict__ m_vyy, float* __restrict__ m_vyx,
    float* __restrict__ m_vxy, float* __restrict__ m_vxx,
    const float* __restrict__ lamb, const float* __restrict__ mu,
    const float* __restrict__ pa, const float* __restrict__ pb,
    const int* __restrict__ recloc, float* __restrict__ out, int t)
{
    int s, y, xb;
    swizzle_block(s, y, xb);
    int x = xb * 256 + threadIdx.x;
    int sbase = s * NY * NX;
    int idx = sbase + y * NX + x;
    const float inv_dx = 1.0f / DXF;

    // receiver recording: vy is read-only in this kernel. 256 = NSHOT*NREC.
    if (blockIdx.x == 0 && blockIdx.y == 0 && blockIdx.z == 0) {
        int p = threadIdx.x;
        if (p < NSHOT * NREC) {
            int sh = p / NREC, r = p % NREC;
            int ry = recloc[(sh * NREC + r) * 2 + 0];
            int rx = recloc[(sh * NREC + r) * 2 + 1];
            out[(sh * NREC + r) * NT + t] = vy[sh * NY * NX + ry * NX + rx];
        }
    }

    // dvyy = diff_plus(vy, y)
    float vy_0   = vy[idx];
    float vy_ym1 = ldz(vy, sbase, y - 1, x);
    float vy_yp1 = ldz(vy, sbase, y + 1, x);
    float vy_yp2 = ldz(vy, sbase, y + 2, x);
    float dvyy = (C1F * (vy_yp1 - vy_0) + C2F * (vy_yp2 - vy_ym1)) * inv_dx;

    // dvxx = diff_plus(vx, x)
    float vx_0   = vx[idx];
    float vx_xm1 = ldz(vx, sbase, y, x - 1);
    float vx_xp1 = ldz(vx, sbase, y, x + 1);
    float vx_xp2 = ldz(vx, sbase, y, x + 2);
    float dvxx = (C1F * (vx_xp1 - vx_0) + C2F * (vx_xp2 - vx_xm1)) * inv_dx;

    // dvyx = diff_minus(vy, x)
    float vy_xm1 = ldz(vy, sbase, y, x - 1);
    float vy_xm2 = ldz(vy, sbase, y, x - 2);
    float vy_xp1 = ldz(vy, sbase, y, x + 1);
    float dvyx = (C1F * (vy_0 - vy_xm1) + C2F * (vy_xp1 - vy_xm2)) * inv_dx;

    // dvxy = diff_minus(vx, y)
    float vx_ym1 = ldz(vx, sbase, y - 1, x);
    float vx_ym2 = ldz(vx, sbase, y - 2, x);
    float vx_yp1 = ldz(vx, sbase, y + 1, x);
    float dvxy = (C1F * (vx_0 - vx_ym1) + C2F * (vx_yp1 - vx_ym2)) * inv_dx;

    // y-direction PML memory fields (uniform branch)
    float mvyy = 0.0f, mvxy = 0.0f;
    if (in_pml(y)) {
        float ay = pa[y], by = pb[y];
        mvyy = by * m_vyy[idx] + ay * dvyy; m_vyy[idx] = mvyy;
        mvxy = by * m_vxy[idx] + ay * dvxy; m_vxy[idx] = mvxy;
    }
    // x-direction PML memory fields (lane-masked)
    float mvxx = 0.0f, mvyx = 0.0f;
    if (in_pml(x)) {
        float ax = pa[x], bx = pb[x];
        mvxx = bx * m_vxx[idx] + ax * dvxx; m_vxx[idx] = mvxx;
        mvyx = bx * m_vyx[idx] + ax * dvyx; m_vyx[idx] = mvyx;
    }

    float tvyy = dvyy + mvyy;
    float tvxx = dvxx + mvxx;

    float la = lamb[y * NX + x];
    float m  = mu[y * NX + x];
    float l2m = la + 2.0f * m;
    syy[idx] += DTF * (l2m * tvyy + la * tvxx);
    sxx[idx] += DTF * (l2m * tvxx + la * tvyy);
    sxy[idx] += DTF * m * ((dvyx + mvyx) + (dvxy + mvxy));
}

extern "C" void kernel_launch(void* const* d_in, const int* in_sizes, int n_in,
                              void* d_out, int out_size, void* d_ws, size_t ws_size,
                              hipStream_t stream) {
    const float* lamb  = (const float*)d_in[0];
    const float* mu    = (const float*)d_in[1];
    const float* buoy  = (const float*)d_in[2];
    const float* amps  = (const float*)d_in[3];
    const int*   srcloc = (const int*)d_in[4];
    const int*   recloc = (const int*)d_in[5];
    float* out = (float*)d_out;

    float* ws = (float*)d_ws;
    float* pa = ws;
    float* pb = ws + 512;
    const size_t F = (size_t)NSHOT * NY * NX;
    float* fields = ws + 1024;
    float* vy     = fields + 0  * F;
    float* vx     = fields + 1  * F;
    float* syy    = fields + 2  * F;
    float* sxy    = fields + 3  * F;
    float* sxx    = fields + 4  * F;
    float* m_vyy  = fields + 5  * F;
    float* m_vyx  = fields + 6  * F;
    float* m_vxy  = fields + 7  * F;
    float* m_vxx  = fields + 8  * F;
    float* m_syyy = fields + 9  * F;
    float* m_sxyy = fields + 10 * F;
    float* m_sxyx = fields + 11 * F;
    float* m_sxxx = fields + 12 * F;

    // workspace is poisoned 0xAA before every call — zero the state
    hipMemsetAsync(fields, 0, 13 * F * sizeof(float), stream);
    init_profiles<<<2, 256, 0, stream>>>(pa, pb);

    dim3 grid(NX / 256, NY, NSHOT);
    dim3 block(256);
    for (int t = 0; t < NT; ++t) {
        vel_kernel<<<grid, block, 0, stream>>>(syy, sxy, sxx, vy, vx,
                                               m_syyy, m_sxyy, m_sxyx, m_sxxx,
                                               buoy, pa, pb, amps, srcloc, t);
        stress_kernel<<<grid, block, 0, stream>>>(vy, vx, syy, sxy, sxx,
                                                  m_vyy, m_vyx, m_vxy, m_vxx,
                                                  lamb, mu, pa, pb, recloc, out, t);
    }
}